// Round 7
// baseline (578.654 us; speedup 1.0000x reference)
//
#include <hip/hip_runtime.h>
#include <math.h>

#define NN 50000      // nodes
#define DD 128        // embedding dim
#define K2D 256       // 2*D (pair width)
#define HH 256        // hidden
#define EE 400000     // edges
#define TE 64         // rows per block (res / fallback det)
#define RT 64         // flagged edges per refine tile
#define PST 260       // padded fp32 LDS row stride
#define TAU  0.02f    // |z_bf16| band -> fp32 refine
#define TAU2 5e-5f    // |z_fp32| band -> fp64 decide

typedef __attribute__((ext_vector_type(8))) short bf16x8;
typedef __attribute__((ext_vector_type(4))) float f32x4;
typedef unsigned int uint;
typedef unsigned short ushort;

typedef __attribute__((address_space(3))) void lds_void_t;
typedef __attribute__((address_space(1))) void g1_void_t;

__device__ __forceinline__ ushort f2bf(float x) {
    uint u = __builtin_bit_cast(uint, x);
    u = (u + 0x7FFFu + ((u >> 16) & 1u)) >> 16;   // RNE
    return (ushort)u;
}
__device__ __forceinline__ float bf2f(ushort x) {
    return __builtin_bit_cast(float, (uint)x << 16);
}

// LDS A-tile in MFMA A-fragment order (round-2 derivation):
// (r,k) -> sid=(r>>4)*8+(k>>5), lane=((k>>3)&3)*16+(r&15), j=k&7
__device__ __forceinline__ int stageOff(int r, int k) {
    return ((r >> 4) * 8 + (k >> 5)) * 512 + ((((k >> 3) & 3) << 4) + (r & 15)) * 8 + (k & 7);
}

// ---------------------------------------------------------------------------
// emb fp32 -> bf16 (one pass; RNE identical to f2bf staging)
// ---------------------------------------------------------------------------
__global__ __launch_bounds__(256) void conv_kernel(const float* __restrict__ emb,
                                                   ushort* __restrict__ out)
{
    const int i = blockIdx.x * 256 + threadIdx.x;
    if (i >= NN * DD / 8) return;
    const float4 a = ((const float4*)emb)[(size_t)i * 2];
    const float4 b = ((const float4*)emb)[(size_t)i * 2 + 1];
    uint4 p;
    p.x = (uint)f2bf(a.x) | ((uint)f2bf(a.y) << 16);
    p.y = (uint)f2bf(a.z) | ((uint)f2bf(a.w) << 16);
    p.z = (uint)f2bf(b.x) | ((uint)f2bf(b.y) << 16);
    p.w = (uint)f2bf(b.z) | ((uint)f2bf(b.w) << 16);
    *(uint4*)(out + (size_t)i * 8) = p;
}

// ---------------------------------------------------------------------------
// Weight swizzle: W (rows x N fp32 row-major) -> bf16 MFMA B-frag order.
// out[((n*Kt + t)*64 + lane)*8 + j] = W[t*32 + (lane>>4)*8 + j][n*16 + (lane&15)]
// ---------------------------------------------------------------------------
__global__ __launch_bounds__(64) void swz_kernel(const float* __restrict__ W,
                                                 ushort* __restrict__ out,
                                                 int N, int Kt)
{
    const int bid = blockIdx.x;
    const int n = bid / Kt, t = bid - n * Kt;
    const int l = threadIdx.x;
    const int row0 = t * 32 + (l >> 4) * 8;
    const int col = n * 16 + (l & 15);
    ushort tmp[8];
#pragma unroll
    for (int j = 0; j < 8; ++j) tmp[j] = f2bf(W[(row0 + j) * N + col]);
    uint4 p;
    p.x = (uint)tmp[0] | ((uint)tmp[1] << 16);
    p.y = (uint)tmp[2] | ((uint)tmp[3] << 16);
    p.z = (uint)tmp[4] | ((uint)tmp[5] << 16);
    p.w = (uint)tmp[6] | ((uint)tmp[7] << 16);
    *(uint4*)(out + ((size_t)bid * 64 + l) * 8) = p;
}

// ---------------------------------------------------------------------------
// UV GEMM: UV[node][0:256] = emb@W1_top, UV[node][256:512] = emb@W1_bot.
// 512 thr / 8 waves; tile 64 nodes x 512 cols; K=128 (4 k-tiles).
// A-frags loaded DIRECTLY from global embbf (sequential nodes, L1-reused);
// no LDS, no barriers. Output stored bf16.
// ---------------------------------------------------------------------------
__global__ __launch_bounds__(512) void uv_kernel(
    const ushort* __restrict__ embbf,
    const ushort* __restrict__ wus,   // Wd1 rows 0..127, B-frag (N=256,Kt=4)
    const ushort* __restrict__ wvs,   // Wd1 rows 128..255
    ushort* __restrict__ uv)
{
    const int tid = threadIdx.x;
    const int wv = tid >> 6;          // 0..7: cols wv*64..+63 of 512
    const int lane = tid & 63;
    const int lc = lane & 15, lg = lane >> 4;
    const int n0 = blockIdx.x * 64;

    const ushort* wbase = ((wv < 4) ? wus : wvs) + (size_t)((wv & 3) * 4) * 4 * 512;

    f32x4 acc[4][4] = {};
#pragma unroll
    for (int kt = 0; kt < 4; ++kt) {
        bf16x8 af[4], bfr[4];
#pragma unroll
        for (int m = 0; m < 4; ++m) {
            const int row = min(n0 + m * 16 + lc, NN - 1);
            af[m] = *(const bf16x8*)(embbf + (size_t)row * DD + kt * 32 + lg * 8);
        }
#pragma unroll
        for (int n = 0; n < 4; ++n)
            bfr[n] = *(const bf16x8*)(wbase + ((n * 4 + kt) * 64 + lane) * 8);
#pragma unroll
        for (int m = 0; m < 4; ++m)
#pragma unroll
            for (int n = 0; n < 4; ++n)
                acc[m][n] = __builtin_amdgcn_mfma_f32_16x16x32_bf16(af[m], bfr[n], acc[m][n], 0, 0, 0);
    }

    const int colbase = wv * 64;
#pragma unroll
    for (int m = 0; m < 4; ++m)
#pragma unroll
        for (int n = 0; n < 4; ++n)
#pragma unroll
            for (int r = 0; r < 4; ++r) {
                const int row = n0 + m * 16 + lg * 4 + r;
                if (row < NN)
                    uv[(size_t)row * 512 + colbase + n * 16 + lc] = f2bf(acc[m][n][r]);
            }
}

// ---------------------------------------------------------------------------
// Edge pass: one wave per edge (grid-stride), 2-deep software pipeline.
// z = sum_j relu(U[src][j] + V[dst][j] + b1[j]) * W2[j] + b2.
// Contiguous 512B row reads; full occupancy (no LDS, low VGPR).
// ---------------------------------------------------------------------------
__global__ __launch_bounds__(256) void det_edge(
    const ushort* __restrict__ uv,
    const int* __restrict__ srcIdx, const int* __restrict__ dstIdx,
    const float* __restrict__ b1, const float* __restrict__ W2,
    const float* __restrict__ b2p,
    float* __restrict__ scores,
    int* __restrict__ last,
    int* __restrict__ flagCount, int* __restrict__ flagList, int flagCap)
{
    const int lane = threadIdx.x & 63;
    const int wid = blockIdx.x * (blockDim.x >> 6) + (threadIdx.x >> 6);
    const int nw = gridDim.x * (blockDim.x >> 6);

    float b1l[4], w2l[4];
#pragma unroll
    for (int i = 0; i < 4; ++i) {
        b1l[i] = b1[lane * 4 + i];
        w2l[i] = W2[lane * 4 + i];
    }
    const float b2v = *b2p;

    int e = wid;
    if (e >= EE) return;
    // pipeline state: (s0,d0,u,v) = current edge rows; (s1,d1) = next indices
    int s0 = srcIdx[e], d0 = dstIdx[e];
    ushort4 u = *(const ushort4*)(uv + (size_t)s0 * 512 + lane * 4);
    ushort4 v = *(const ushort4*)(uv + (size_t)d0 * 512 + 256 + lane * 4);
    int en = e + nw;
    int s1 = 0, d1 = 0;
    if (en < EE) { s1 = srcIdx[en]; d1 = dstIdx[en]; }

    for (; e < EE; e += nw) {
        en = e + nw;
        ushort4 un, vn;
        if (en < EE) {   // issue next rows early: latency hidden by compute
            un = *(const ushort4*)(uv + (size_t)s1 * 512 + lane * 4);
            vn = *(const ushort4*)(uv + (size_t)d1 * 512 + 256 + lane * 4);
        }
        const int enn = en + nw;
        int s2 = 0, d2 = 0;
        if (enn < EE) { s2 = srcIdx[enn]; d2 = dstIdx[enn]; }

        float z = 0.f;
        z = fmaf(fmaxf(bf2f(u.x) + bf2f(v.x) + b1l[0], 0.f), w2l[0], z);
        z = fmaf(fmaxf(bf2f(u.y) + bf2f(v.y) + b1l[1], 0.f), w2l[1], z);
        z = fmaf(fmaxf(bf2f(u.z) + bf2f(v.z) + b1l[2], 0.f), w2l[2], z);
        z = fmaf(fmaxf(bf2f(u.w) + bf2f(v.w) + b1l[3], 0.f), w2l[3], z);
#pragma unroll
        for (int m = 1; m <= 32; m <<= 1) z += __shfl_xor(z, m, 64);

        if (lane == 0) {
            const float zt = z + b2v;
            scores[e] = 1.0f / (1.0f + expf(-zt));
            bool deferred = false;
            if (fabsf(zt) < TAU) {
                const int slot = atomicAdd(flagCount, 1);
                if (slot < flagCap) { flagList[slot] = e; deferred = true; }
            }
            if (!deferred && zt > 0.0f) {
                atomicMax(&last[s0], e + 1);
                atomicMax(&last[d0], e + 1);
            }
        }
        u = un; v = vn;
        s0 = s1; d0 = d1;
        s1 = s2; d1 = d2;
    }
}

// ---------------------------------------------------------------------------
// Fallback detector (round-5 structure, fp32 staging) for tiny workspaces.
// ---------------------------------------------------------------------------
__global__ __launch_bounds__(256) void det_kernel(
    const float* __restrict__ emb,
    const int* __restrict__ srcIdx, const int* __restrict__ dstIdx,
    const ushort* __restrict__ w1s, const float* __restrict__ b1,
    const float* __restrict__ W2, const float* __restrict__ b2p,
    float* __restrict__ scores,
    int* __restrict__ last,
    int* __restrict__ flagCount, int* __restrict__ flagList, int flagCap)
{
    __shared__ __align__(16) ushort A_lds[TE * K2D];
    __shared__ float zp[256];
    const int tid = threadIdx.x;
    const int e0 = blockIdx.x * TE;
    {
        const int r = tid >> 2, q = tid & 3;
        const int e = e0 + r;
        const int node = (q < 2) ? srcIdx[e] : dstIdx[e];
        const float4* s4 = (const float4*)(emb + (size_t)node * DD + (q & 1) * 64);
#pragma unroll
        for (int u = 0; u < 16; ++u) {
            const float4 v = s4[u];
            const int k0 = q * 64 + u * 4;
            uint2 p;
            p.x = (uint)f2bf(v.x) | ((uint)f2bf(v.y) << 16);
            p.y = (uint)f2bf(v.z) | ((uint)f2bf(v.w) << 16);
            *(uint2*)&A_lds[stageOff(r, k0)] = p;
        }
    }
    __syncthreads();

    const int wv = tid >> 6;
    const int lane = tid & 63;
    const int lc = lane & 15, lg = lane >> 4;

    f32x4 acc[4][4] = {};
    const ushort* wbase = w1s + (size_t)(wv * 4) * 8 * 512;
#pragma unroll 2
    for (int t = 0; t < 8; ++t) {
        bf16x8 af[4], bfr[4];
#pragma unroll
        for (int m = 0; m < 4; ++m)
            af[m] = *(const bf16x8*)&A_lds[(m * 8 + t) * 512 + lane * 8];
#pragma unroll
        for (int n = 0; n < 4; ++n)
            bfr[n] = *(const bf16x8*)(wbase + (n * 8 + t) * 512 + lane * 8);
#pragma unroll
        for (int m = 0; m < 4; ++m)
#pragma unroll
            for (int n = 0; n < 4; ++n)
                acc[m][n] = __builtin_amdgcn_mfma_f32_16x16x32_bf16(af[m], bfr[n], acc[m][n], 0, 0, 0);
    }
    float b1v[4], w2v[4];
#pragma unroll
    for (int n = 0; n < 4; ++n) {
        const int col = wv * 64 + n * 16 + lc;
        b1v[n] = b1[col];
        w2v[n] = W2[col];
    }
    float pz[4][4];
#pragma unroll
    for (int m = 0; m < 4; ++m)
#pragma unroll
        for (int r = 0; r < 4; ++r) {
            float s = 0.f;
#pragma unroll
            for (int n = 0; n < 4; ++n)
                s = fmaf(fmaxf(acc[m][n][r] + b1v[n], 0.f), w2v[n], s);
            pz[m][r] = s;
        }
#pragma unroll
    for (int msk = 1; msk <= 8; msk <<= 1)
#pragma unroll
        for (int m = 0; m < 4; ++m)
#pragma unroll
            for (int r = 0; r < 4; ++r)
                pz[m][r] += __shfl_xor(pz[m][r], msk, 64);
    if (lc == 0) {
#pragma unroll
        for (int m = 0; m < 4; ++m)
#pragma unroll
            for (int r = 0; r < 4; ++r)
                zp[wv * 64 + m * 16 + lg * 4 + r] = pz[m][r];
    }
    __syncthreads();
    if (tid < 64) {
        const int e = e0 + tid;
        const float z = zp[tid] + zp[64 + tid] + zp[128 + tid] + zp[192 + tid] + *b2p;
        scores[e] = 1.0f / (1.0f + expf(-z));
        bool deferred = false;
        if (fabsf(z) < TAU) {
            const int slot = atomicAdd(flagCount, 1);
            if (slot < flagCap) { flagList[slot] = e; deferred = true; }
        }
        if (!deferred && z > 0.0f) {
            atomicMax(&last[srcIdx[e]], e + 1);
            atomicMax(&last[dstIdx[e]], e + 1);
        }
    }
}

// ---------------------------------------------------------------------------
// Stage B: fp32 refine, tiled (64 flagged edges/block so W1 is amortized).
// ---------------------------------------------------------------------------
__global__ __launch_bounds__(256) void refine32_kernel(
    const float* __restrict__ emb,
    const int* __restrict__ srcIdx, const int* __restrict__ dstIdx,
    const float* __restrict__ W1, const float* __restrict__ b1,
    const float* __restrict__ W2, const float* __restrict__ b2p,
    int* __restrict__ last,
    const int* __restrict__ flagCount, const int* __restrict__ flagList, int flagCap,
    int* __restrict__ flagCount2, int* __restrict__ flagList2, int flagCap2)
{
    __shared__ __align__(16) float P[RT * PST];
    __shared__ int eL[RT];
    const int tid = threadIdx.x;
    const int cnt = min(*flagCount, flagCap);
    const int nTiles = (cnt + RT - 1) / RT;
    const float b2v = *b2p;

    for (int T = blockIdx.x; T < nTiles; T += gridDim.x) {
        if (tid < RT) {
            const int idx = T * RT + tid;
            eL[tid] = flagList[min(idx, cnt - 1)];
        }
        __syncthreads();
        {
            const int i = tid >> 2, q = tid & 3;
            const int e = eL[i];
            const int node = (q < 2) ? srcIdx[e] : dstIdx[e];
            const float4* s4 = (const float4*)(emb + (size_t)node * DD + (q & 1) * 64);
            float4* d4 = (float4*)(P + i * PST + q * 64);
#pragma unroll
            for (int t = 0; t < 16; ++t) d4[t] = s4[t];
        }
        __syncthreads();

        const int rowg = tid >> 5;
        const int colg = tid & 31;
        const int c0 = colg * 8;

        float acc[8][8];
#pragma unroll
        for (int c = 0; c < 8; ++c) {
            const float bv = b1[c0 + c];
#pragma unroll
            for (int r = 0; r < 8; ++r) acc[r][c] = bv;
        }
        for (int kk = 0; kk < K2D; kk += 4) {
            float af[8][4];
#pragma unroll
            for (int r = 0; r < 8; ++r) {
                const float4 v = *(const float4*)&P[(rowg * 8 + r) * PST + kk];
                af[r][0] = v.x; af[r][1] = v.y; af[r][2] = v.z; af[r][3] = v.w;
            }
#pragma unroll
            for (int dk = 0; dk < 4; ++dk) {
                const float4 w0 = *(const float4*)&W1[(kk + dk) * HH + c0];
                const float4 w1 = *(const float4*)&W1[(kk + dk) * HH + c0 + 4];
#pragma unroll
                for (int r = 0; r < 8; ++r) {
                    const float av = af[r][dk];
                    acc[r][0] = fmaf(av, w0.x, acc[r][0]);
                    acc[r][1] = fmaf(av, w0.y, acc[r][1]);
                    acc[r][2] = fmaf(av, w0.z, acc[r][2]);
                    acc[r][3] = fmaf(av, w0.w, acc[r][3]);
                    acc[r][4] = fmaf(av, w1.x, acc[r][4]);
                    acc[r][5] = fmaf(av, w1.y, acc[r][5]);
                    acc[r][6] = fmaf(av, w1.z, acc[r][6]);
                    acc[r][7] = fmaf(av, w1.w, acc[r][7]);
                }
            }
        }

        float w2[8];
#pragma unroll
        for (int c = 0; c < 8; ++c) w2[c] = W2[c0 + c];
        float pz[8];
#pragma unroll
        for (int r = 0; r < 8; ++r) {
            float s = 0.f;
#pragma unroll
            for (int c = 0; c < 8; ++c) s = fmaf(fmaxf(acc[r][c], 0.f), w2[c], s);
            pz[r] = s;
        }
#pragma unroll
        for (int m = 1; m <= 16; m <<= 1) {
#pragma unroll
            for (int r = 0; r < 8; ++r) pz[r] += __shfl_xor(pz[r], m, 64);
        }

        if (colg == 0) {
            for (int r = 0; r < 8; ++r) {
                const int row = rowg * 8 + r;
                const int idx = T * RT + row;
                if (idx < cnt) {
                    const int e = eL[row];
                    const int s = srcIdx[e], d = dstIdx[e];
                    const float z = pz[r] + b2v;
                    if (fabsf(z) < TAU2) {
                        const int slot = atomicAdd(flagCount2, 1);
                        if (slot < flagCap2) {
                            flagList2[slot] = e;
                        } else if (z > 0.f) {
                            atomicMax(&last[s], e + 1);
                            atomicMax(&last[d], e + 1);
                        }
                    } else if (z > 0.f) {
                        atomicMax(&last[s], e + 1);
                        atomicMax(&last[d], e + 1);
                    }
                }
            }
        }
        __syncthreads();
    }
}

// ---------------------------------------------------------------------------
// Stage C: fp64 final decision for the remaining ~dozens of edges.
// ---------------------------------------------------------------------------
__global__ __launch_bounds__(256) void refine64_kernel(
    const float* __restrict__ emb,
    const int* __restrict__ srcIdx, const int* __restrict__ dstIdx,
    const float* __restrict__ W1, const float* __restrict__ b1,
    const float* __restrict__ W2, const float* __restrict__ b2p,
    int* __restrict__ last,
    const int* __restrict__ flagCount2, const int* __restrict__ flagList2,
    int flagCap2)
{
    __shared__ float pair[K2D];
    __shared__ double wsumd[4];
    const int tid = threadIdx.x;
    const int cnt = min(*flagCount2, flagCap2);
    for (int f = blockIdx.x; f < cnt; f += gridDim.x) {
        const int e = flagList2[f];
        const int s = srcIdx[e], d = dstIdx[e];
        __syncthreads();
        pair[tid] = (tid < DD) ? emb[(size_t)s * DD + tid]
                               : emb[(size_t)d * DD + tid - DD];
        __syncthreads();
        double h0 = 0.0, h1 = 0.0;
        for (int k = 0; k < K2D; k += 2) {
            h0 += (double)pair[k]     * (double)W1[(k)     * HH + tid];
            h1 += (double)pair[k + 1] * (double)W1[(k + 1) * HH + tid];
        }
        const double h = (double)b1[tid] + h0 + h1;
        double v = (h > 0.0) ? h * (double)W2[tid] : 0.0;
#pragma unroll
        for (int m = 1; m <= 32; m <<= 1) v += __shfl_xor(v, m, 64);
        if ((tid & 63) == 0) wsumd[tid >> 6] = v;
        __syncthreads();
        if (tid == 0) {
            const double z = wsumd[0] + wsumd[1] + wsumd[2] + wsumd[3] + (double)(*b2p);
            if (z > 0.0) {
                atomicMax(&last[s], e + 1);
                atomicMax(&last[d], e + 1);
            }
        }
        __syncthreads();
    }
}

// ---------------------------------------------------------------------------
// Resolver per NODE (winning edge only), both layers bf16 MFMA.
// ---------------------------------------------------------------------------
template<int BF>
__global__ __launch_bounds__(256) void res_kernel(
    const float* __restrict__ emb, const ushort* __restrict__ embbf,
    const int* __restrict__ srcIdx, const int* __restrict__ dstIdx,
    const ushort* __restrict__ w1s, const float* __restrict__ b1,
    const ushort* __restrict__ w2s, const float* __restrict__ b2,
    const int* __restrict__ last,
    float* __restrict__ outRes)
{
    __shared__ __align__(16) ushort A_lds[TE * K2D];
    __shared__ int lastL[TE];
    const int tid = threadIdx.x;
    const int n0 = blockIdx.x * TE;
    const int wv = tid >> 6;
    const int lane = tid & 63;

    if (tid < TE) {
        const int n = n0 + tid;
        lastL[tid] = (n < NN) ? last[n] : 0;
    }
    if (BF) {
        const int r = wv * 16 + (lane & 15);
        const int n = n0 + r;
        int e = 0;
        if (n < NN) { const int lv = last[n]; if (lv > 0) e = lv - 1; }
        const int ns = srcIdx[e], nd = dstIdx[e];
        const int ko = (lane >> 4) * 8;
#pragma unroll
        for (int s = 0; s < 8; ++s) {
            const int node = (s < 4) ? ns : nd;
            const ushort* g = embbf + (size_t)node * DD + (s & 3) * 32 + ko;
            __builtin_amdgcn_global_load_lds((const g1_void_t*)g,
                                             (lds_void_t*)&A_lds[(wv * 8 + s) * 512],
                                             16, 0, 0);
        }
    } else {
        const int r = tid >> 2, q = tid & 3;
        const int n = n0 + r;
        int e = 0;
        if (n < NN) { const int l = last[n]; if (l > 0) e = l - 1; }
        const int node = (q < 2) ? srcIdx[e] : dstIdx[e];
        const float4* s4 = (const float4*)(emb + (size_t)node * DD + (q & 1) * 64);
#pragma unroll
        for (int u = 0; u < 16; ++u) {
            const float4 v = s4[u];
            const int k0 = q * 64 + u * 4;
            uint2 p;
            p.x = (uint)f2bf(v.x) | ((uint)f2bf(v.y) << 16);
            p.y = (uint)f2bf(v.z) | ((uint)f2bf(v.w) << 16);
            *(uint2*)&A_lds[stageOff(r, k0)] = p;
        }
    }
    __syncthreads();

    const int lc = lane & 15, lg = lane >> 4;

    f32x4 acc[4][4] = {};
    {
        const ushort* wbase = w1s + (size_t)(wv * 4) * 8 * 512;
#pragma unroll 2
        for (int t = 0; t < 8; ++t) {
            bf16x8 af[4], bfr[4];
#pragma unroll
            for (int m = 0; m < 4; ++m)
                af[m] = *(const bf16x8*)&A_lds[(m * 8 + t) * 512 + lane * 8];
#pragma unroll
            for (int n = 0; n < 4; ++n)
                bfr[n] = *(const bf16x8*)(wbase + (n * 8 + t) * 512 + lane * 8);
#pragma unroll
            for (int m = 0; m < 4; ++m)
#pragma unroll
                for (int n = 0; n < 4; ++n)
                    acc[m][n] = __builtin_amdgcn_mfma_f32_16x16x32_bf16(af[m], bfr[n], acc[m][n], 0, 0, 0);
        }
    }
    float b1v[4];
#pragma unroll
    for (int n = 0; n < 4; ++n) b1v[n] = b1[wv * 64 + n * 16 + lc];

    __syncthreads();
#pragma unroll
    for (int m = 0; m < 4; ++m)
#pragma unroll
        for (int n = 0; n < 4; ++n) {
            const int hcol = wv * 64 + n * 16 + lc;
#pragma unroll
            for (int r = 0; r < 4; ++r) {
                const int row = m * 16 + lg * 4 + r;
                A_lds[stageOff(row, hcol)] = f2bf(fmaxf(acc[m][n][r] + b1v[n], 0.f));
            }
        }
    __syncthreads();

    f32x4 acc2[4][2] = {};
    {
        const ushort* wbase = w2s + (size_t)(wv * 2) * 8 * 512;
#pragma unroll 2
        for (int t = 0; t < 8; ++t) {
            bf16x8 af[4], bfr[2];
#pragma unroll
            for (int m = 0; m < 4; ++m)
                af[m] = *(const bf16x8*)&A_lds[(m * 8 + t) * 512 + lane * 8];
#pragma unroll
            for (int n = 0; n < 2; ++n)
                bfr[n] = *(const bf16x8*)(wbase + (n * 8 + t) * 512 + lane * 8);
#pragma unroll
            for (int m = 0; m < 4; ++m)
#pragma unroll
                for (int n = 0; n < 2; ++n)
                    acc2[m][n] = __builtin_amdgcn_mfma_f32_16x16x32_bf16(af[m], bfr[n], acc2[m][n], 0, 0, 0);
        }
    }
    float b2v[2];
#pragma unroll
    for (int n = 0; n < 2; ++n) b2v[n] = b2[(wv * 2 + n) * 16 + lc];

#pragma unroll
    for (int m = 0; m < 4; ++m)
#pragma unroll
        for (int r = 0; r < 4; ++r) {
            const int row = m * 16 + lg * 4 + r;
            const int n = n0 + row;
            if (n >= NN) continue;
            const bool hit = lastL[row] > 0;
#pragma unroll
            for (int c = 0; c < 2; ++c) {
                const int col = (wv * 2 + c) * 16 + lc;
                const float ev = emb[(size_t)n * DD + col];
                outRes[(size_t)n * DD + col] =
                    hit ? (ev + acc2[m][c][r] + b2v[c]) * 0.5f : ev;
            }
        }
}

// ---------------------------------------------------------------------------
extern "C" void kernel_launch(void* const* d_in, const int* in_sizes, int n_in,
                              void* d_out, int out_size, void* d_ws, size_t ws_size,
                              hipStream_t stream)
{
    const float* emb = (const float*)d_in[0];
    const int*   edge = (const int*)d_in[1];
    const float* Wd1 = (const float*)d_in[2];
    const float* bd1 = (const float*)d_in[3];
    const float* Wd2 = (const float*)d_in[4];
    const float* bd2 = (const float*)d_in[5];
    const float* Wr1 = (const float*)d_in[6];
    const float* br1 = (const float*)d_in[7];
    const float* Wr2 = (const float*)d_in[8];
    const float* br2 = (const float*)d_in[9];

    const int* srcIdx = edge;
    const int* dstIdx = edge + EE;

    float* outRes = (float*)d_out;
    float* scores = outRes + (size_t)NN * DD;

    // ws layout: last[50000+pad] | counters | bf16 weights (5 blocks) |
    //            flagLists | embbf (12.8MB) | uv (51.2MB)
    int* last = (int*)d_ws;
    int* flagCount  = last + 50112;
    int* flagCount2 = last + 50113;
    ushort* wd1s  = (ushort*)(last + 50176);   // 65536 ush (fallback, K=256)
    ushort* wr1s  = wd1s + 65536;              // 65536
    ushort* wr2s  = wr1s + 65536;              // 32768
    ushort* wd1us = wr2s + 32768;              // 32768 (Wd1 rows 0..127)
    ushort* wd1vs = wd1us + 32768;             // 32768 (Wd1 rows 128..255)
    int* flagList  = (int*)(wd1vs + 32768);    // 65536 ints
    int* flagList2 = flagList + 65536;         // 8192 ints
    ushort* embbf  = (ushort*)(flagList2 + 8192);      // NN*DD ush
    ushort* uvbuf  = embbf + (size_t)NN * DD;          // NN*512 ush

    const size_t base   = 50176u * 4 + 229376u * 2 + (65536u + 8192u) * 4;
    const size_t needBF = base + (size_t)NN * DD * 2;
    const size_t needUV = needBF + (size_t)NN * 512 * 2;
    const int useBF = (ws_size >= needBF) ? 1 : 0;
    const int useUV = (ws_size >= needUV) ? 1 : 0;

    long wsInts = (long)(ws_size / 4);
    long avail = wsInts - (long)(base / 4) + 65536 + 8192;
    int flagCap  = 65536;
    int flagCap2 = 8192;
    if (avail < 65536 + 8192) {
        flagCap  = avail > 8192 ? (int)(avail - 8192) : 0;
        flagCap2 = avail > 8192 ? 8192 : (avail < 0 ? 0 : (int)avail);
    }

    hipMemsetAsync(d_ws, 0, 50176 * sizeof(int), stream);   // last + counters

    if (useBF)
        conv_kernel<<<(NN * DD / 8 + 255) / 256, 256, 0, stream>>>(emb, embbf);
    swz_kernel<<<128, 64, 0, stream>>>(Wr1, wr1s, HH, 8);
    swz_kernel<<<64, 64, 0, stream>>>(Wr2, wr2s, DD, 8);

    if (useUV) {
        // detector via per-node linearization: UV GEMM + streaming edge pass
        swz_kernel<<<64, 64, 0, stream>>>(Wd1, wd1us, HH, 4);            // rows 0..127
        swz_kernel<<<64, 64, 0, stream>>>(Wd1 + 128 * HH, wd1vs, HH, 4); // rows 128..255
        uv_kernel<<<(NN + 63) / 64, 512, 0, stream>>>(embbf, wd1us, wd1vs, uvbuf);
        det_edge<<<2048, 256, 0, stream>>>(uvbuf, srcIdx, dstIdx,
                                           bd1, Wd2, bd2,
                                           scores, last, flagCount, flagList, flagCap);
    } else {
        swz_kernel<<<128, 64, 0, stream>>>(Wd1, wd1s, HH, 8);
        det_kernel<<<EE / TE, 256, 0, stream>>>(emb, srcIdx, dstIdx,
                                                wd1s, bd1, Wd2, bd2,
                                                scores, last, flagCount, flagList, flagCap);
    }
    refine32_kernel<<<512, 256, 0, stream>>>(emb, srcIdx, dstIdx,
                                             Wd1, bd1, Wd2, bd2,
                                             last, flagCount, flagList, flagCap,
                                             flagCount2, flagList2, flagCap2);
    refine64_kernel<<<512, 256, 0, stream>>>(emb, srcIdx, dstIdx,
                                             Wd1, bd1, Wd2, bd2,
                                             last, flagCount2, flagList2, flagCap2);
    if (useBF) {
        res_kernel<1><<<(NN + TE - 1) / TE, 256, 0, stream>>>(emb, embbf, srcIdx, dstIdx,
                                                              wr1s, br1, wr2s, br2,
                                                              last, outRes);
    } else {
        res_kernel<0><<<(NN + TE - 1) / TE, 256, 0, stream>>>(emb, embbf, srcIdx, dstIdx,
                                                              wr1s, br1, wr2s, br2,
                                                              last, outRes);
    }
}

// Round 8
// 255.164 us; speedup vs baseline: 2.2678x; 2.2678x over previous
//
#include <hip/hip_runtime.h>
#include <math.h>

#define NN 50000      // nodes
#define DD 128        // embedding dim
#define K2D 256       // 2*D (pair width)
#define HH 256        // hidden
#define EE 400000     // edges
#define TE 64         // rows per block (det / res)
#define RT 32         // flagged edges per refine tile
#define PST 260       // padded fp32 LDS row stride
#define TAU  0.02f    // |z_bf16| band -> fp32 refine
#define TAU2 5e-5f    // |z_fp32| band -> fp64 decide (inline)

typedef __attribute__((ext_vector_type(8))) short bf16x8;
typedef __attribute__((ext_vector_type(4))) float f32x4;
typedef unsigned int uint;
typedef unsigned short ushort;

typedef __attribute__((address_space(3))) void lds_void_t;
typedef __attribute__((address_space(1))) void g1_void_t;

__device__ __forceinline__ ushort f2bf(float x) {
    uint u = __builtin_bit_cast(uint, x);
    u = (u + 0x7FFFu + ((u >> 16) & 1u)) >> 16;   // RNE
    return (ushort)u;
}

// LDS A-tile in MFMA A-fragment order (round-2 derivation):
// (r,k) -> sid=(r>>4)*8+(k>>5), lane=((k>>3)&3)*16+(r&15), j=k&7
__device__ __forceinline__ int stageOff(int r, int k) {
    return ((r >> 4) * 8 + (k >> 5)) * 512 + ((((k >> 3) & 3) << 4) + (r & 15)) * 8 + (k & 7);
}

__device__ __forceinline__ void swz_unit(const float* __restrict__ W,
                                         ushort* __restrict__ out,
                                         int N, int Kt, int unit, int l)
{
    const int n = unit / Kt, t = unit - n * Kt;
    const int row0 = t * 32 + (l >> 4) * 8;
    const int col = n * 16 + (l & 15);
    ushort tmp[8];
#pragma unroll
    for (int j = 0; j < 8; ++j) tmp[j] = f2bf(W[(row0 + j) * N + col]);
    uint4 p;
    p.x = (uint)tmp[0] | ((uint)tmp[1] << 16);
    p.y = (uint)tmp[2] | ((uint)tmp[3] << 16);
    p.z = (uint)tmp[4] | ((uint)tmp[5] << 16);
    p.w = (uint)tmp[6] | ((uint)tmp[7] << 16);
    *(uint4*)(out + ((size_t)unit * 64 + l) * 8) = p;
}

// ---------------------------------------------------------------------------
// PREP (one dispatch): emb fp32->bf16 (blocks 0..3124) + weight swizzles
// (blocks 3125..3204: Wd1 x32, Wr1 x32, Wr2 x16 -- each 256-thr block = 4
// 64-lane swizzle units).
// ---------------------------------------------------------------------------
__global__ __launch_bounds__(256) void prep_kernel(
    const float* __restrict__ emb, ushort* __restrict__ embbf, int doConv,
    const float* __restrict__ Wd1, ushort* __restrict__ wd1s,
    const float* __restrict__ Wr1, ushort* __restrict__ wr1s,
    const float* __restrict__ Wr2, ushort* __restrict__ wr2s)
{
    const int gid = blockIdx.x;
    const int tid = threadIdx.x;
    if (gid < 3125) {
        if (!doConv) return;
        const int i = gid * 256 + tid;            // 3125*256 == NN*DD/8 exactly
        const float4 a = ((const float4*)emb)[(size_t)i * 2];
        const float4 b = ((const float4*)emb)[(size_t)i * 2 + 1];
        uint4 p;
        p.x = (uint)f2bf(a.x) | ((uint)f2bf(a.y) << 16);
        p.y = (uint)f2bf(a.z) | ((uint)f2bf(a.w) << 16);
        p.z = (uint)f2bf(b.x) | ((uint)f2bf(b.y) << 16);
        p.w = (uint)f2bf(b.z) | ((uint)f2bf(b.w) << 16);
        *(uint4*)(embbf + (size_t)i * 8) = p;
        return;
    }
    const int sub = tid >> 6, l = tid & 63;
    if (gid < 3125 + 32) {
        swz_unit(Wd1, wd1s, HH, 8, (gid - 3125) * 4 + sub, l);         // 128 units
    } else if (gid < 3125 + 64) {
        swz_unit(Wr1, wr1s, HH, 8, (gid - 3125 - 32) * 4 + sub, l);    // 128 units
    } else {
        swz_unit(Wr2, wr2s, DD, 8, (gid - 3125 - 64) * 4 + sub, l);    // 64 units
    }
}

// ---------------------------------------------------------------------------
// Detector (round-5 proven): z = relu(pair@Wd1+b1)@Wd2+b2 via bf16 MFMA;
// flag |z|<TAU. BF=1: DMA-stage bf16 emb into frag-order LDS.
// ---------------------------------------------------------------------------
template<int BF>
__global__ __launch_bounds__(256) void det_kernel(
    const float* __restrict__ emb, const ushort* __restrict__ embbf,
    const int* __restrict__ srcIdx, const int* __restrict__ dstIdx,
    const ushort* __restrict__ w1s, const float* __restrict__ b1,
    const float* __restrict__ W2, const float* __restrict__ b2p,
    float* __restrict__ scores,
    int* __restrict__ last,
    int* __restrict__ flagCount, int* __restrict__ flagList, int flagCap)
{
    __shared__ __align__(16) ushort A_lds[TE * K2D];   // 32 KB, frag order
    __shared__ float zp[256];
    const int tid = threadIdx.x;
    const int e0 = blockIdx.x * TE;
    const int wv = tid >> 6;
    const int lane = tid & 63;

    if (BF) {
        const int r = wv * 16 + (lane & 15);
        const int e = e0 + r;
        const int ns = srcIdx[e], nd = dstIdx[e];
        const int ko = (lane >> 4) * 8;
#pragma unroll
        for (int s = 0; s < 8; ++s) {
            const int node = (s < 4) ? ns : nd;
            const ushort* g = embbf + (size_t)node * DD + (s & 3) * 32 + ko;
            __builtin_amdgcn_global_load_lds((const g1_void_t*)g,
                                             (lds_void_t*)&A_lds[(wv * 8 + s) * 512],
                                             16, 0, 0);
        }
    } else {
        const int r = tid >> 2, q = tid & 3;
        const int e = e0 + r;
        const int node = (q < 2) ? srcIdx[e] : dstIdx[e];
        const float4* s4 = (const float4*)(emb + (size_t)node * DD + (q & 1) * 64);
#pragma unroll
        for (int u = 0; u < 16; ++u) {
            const float4 v = s4[u];
            const int k0 = q * 64 + u * 4;
            uint2 p;
            p.x = (uint)f2bf(v.x) | ((uint)f2bf(v.y) << 16);
            p.y = (uint)f2bf(v.z) | ((uint)f2bf(v.w) << 16);
            *(uint2*)&A_lds[stageOff(r, k0)] = p;
        }
    }
    __syncthreads();

    const int lc = lane & 15, lg = lane >> 4;

    f32x4 acc[4][4] = {};
    const ushort* wbase = w1s + (size_t)(wv * 4) * 8 * 512;

#pragma unroll 2
    for (int t = 0; t < 8; ++t) {
        bf16x8 af[4], bfr[4];
#pragma unroll
        for (int m = 0; m < 4; ++m)
            af[m] = *(const bf16x8*)&A_lds[(m * 8 + t) * 512 + lane * 8];
#pragma unroll
        for (int n = 0; n < 4; ++n)
            bfr[n] = *(const bf16x8*)(wbase + (n * 8 + t) * 512 + lane * 8);
#pragma unroll
        for (int m = 0; m < 4; ++m)
#pragma unroll
            for (int n = 0; n < 4; ++n)
                acc[m][n] = __builtin_amdgcn_mfma_f32_16x16x32_bf16(af[m], bfr[n], acc[m][n], 0, 0, 0);
    }

    float b1v[4], w2v[4];
#pragma unroll
    for (int n = 0; n < 4; ++n) {
        const int col = wv * 64 + n * 16 + lc;
        b1v[n] = b1[col];
        w2v[n] = W2[col];
    }
    float pz[4][4];
#pragma unroll
    for (int m = 0; m < 4; ++m)
#pragma unroll
        for (int r = 0; r < 4; ++r) {
            float s = 0.f;
#pragma unroll
            for (int n = 0; n < 4; ++n)
                s = fmaf(fmaxf(acc[m][n][r] + b1v[n], 0.f), w2v[n], s);
            pz[m][r] = s;
        }
#pragma unroll
    for (int msk = 1; msk <= 8; msk <<= 1)
#pragma unroll
        for (int m = 0; m < 4; ++m)
#pragma unroll
            for (int r = 0; r < 4; ++r)
                pz[m][r] += __shfl_xor(pz[m][r], msk, 64);
    if (lc == 0) {
#pragma unroll
        for (int m = 0; m < 4; ++m)
#pragma unroll
            for (int r = 0; r < 4; ++r)
                zp[wv * 64 + m * 16 + lg * 4 + r] = pz[m][r];
    }
    __syncthreads();

    if (tid < 64) {
        const int e = e0 + tid;
        const float z = zp[tid] + zp[64 + tid] + zp[128 + tid] + zp[192 + tid] + *b2p;
        scores[e] = 1.0f / (1.0f + expf(-z));
        bool deferred = false;
        if (fabsf(z) < TAU) {
            const int slot = atomicAdd(flagCount, 1);
            if (slot < flagCap) { flagList[slot] = e; deferred = true; }
        }
        if (!deferred && z > 0.0f) {
            atomicMax(&last[srcIdx[e]], e + 1);
            atomicMax(&last[dstIdx[e]], e + 1);
        }
    }
}

// ---------------------------------------------------------------------------
// Refine (fp32 tiled GEMM over flagged edges) with INLINE fp64 final decision
// for |z32| < TAU2 (bit-identical inputs/reduce to the old refine64).
// 32 edges/tile -> 34 KB LDS -> ~4 blocks/CU of latency overlap.
// ---------------------------------------------------------------------------
__global__ __launch_bounds__(256) void refine_kernel(
    const float* __restrict__ emb,
    const int* __restrict__ srcIdx, const int* __restrict__ dstIdx,
    const float* __restrict__ W1, const float* __restrict__ b1,
    const float* __restrict__ W2, const float* __restrict__ b2p,
    int* __restrict__ last,
    const int* __restrict__ flagCount, const int* __restrict__ flagList,
    int flagCap)
{
    __shared__ __align__(16) float P[RT * PST];   // 33.3 KB
    __shared__ int eL[RT];
    __shared__ float zs[RT];
    __shared__ int need64[RT];
    __shared__ double wsumd[4];
    const int tid = threadIdx.x;
    const int cnt = min(*flagCount, flagCap);
    const int nTiles = (cnt + RT - 1) / RT;
    const float b2v = *b2p;

    for (int T = blockIdx.x; T < nTiles; T += gridDim.x) {
        if (tid < RT) {
            const int idx = T * RT + tid;
            eL[tid] = flagList[min(idx, cnt - 1)];
            need64[tid] = 0;
        }
        __syncthreads();
        {   // stage pair tile fp32: row i, chunk q of 32 floats
            const int i = tid >> 3, q = tid & 7;
            const int e = eL[i];
            const int node = (q < 4) ? srcIdx[e] : dstIdx[e];
            const float4* s4 = (const float4*)(emb + (size_t)node * DD + (q & 3) * 32);
            float4* d4 = (float4*)(P + i * PST + q * 32);
#pragma unroll
            for (int t = 0; t < 8; ++t) d4[t] = s4[t];
        }
        __syncthreads();

        const int rowg = tid >> 5;    // 0..7, rows rowg*4..+3
        const int colg = tid & 31;
        const int c0 = colg * 8;

        float acc[4][8];
#pragma unroll
        for (int c = 0; c < 8; ++c) {
            const float bv = b1[c0 + c];
#pragma unroll
            for (int r = 0; r < 4; ++r) acc[r][c] = bv;
        }
        for (int kk = 0; kk < K2D; kk += 4) {
            float af[4][4];
#pragma unroll
            for (int r = 0; r < 4; ++r) {
                const float4 v = *(const float4*)&P[(rowg * 4 + r) * PST + kk];
                af[r][0] = v.x; af[r][1] = v.y; af[r][2] = v.z; af[r][3] = v.w;
            }
#pragma unroll
            for (int dk = 0; dk < 4; ++dk) {
                const float4 w0 = *(const float4*)&W1[(kk + dk) * HH + c0];
                const float4 w1 = *(const float4*)&W1[(kk + dk) * HH + c0 + 4];
#pragma unroll
                for (int r = 0; r < 4; ++r) {
                    const float av = af[r][dk];
                    acc[r][0] = fmaf(av, w0.x, acc[r][0]);
                    acc[r][1] = fmaf(av, w0.y, acc[r][1]);
                    acc[r][2] = fmaf(av, w0.z, acc[r][2]);
                    acc[r][3] = fmaf(av, w0.w, acc[r][3]);
                    acc[r][4] = fmaf(av, w1.x, acc[r][4]);
                    acc[r][5] = fmaf(av, w1.y, acc[r][5]);
                    acc[r][6] = fmaf(av, w1.z, acc[r][6]);
                    acc[r][7] = fmaf(av, w1.w, acc[r][7]);
                }
            }
        }

        float w2[8];
#pragma unroll
        for (int c = 0; c < 8; ++c) w2[c] = W2[c0 + c];
        float pz[4];
#pragma unroll
        for (int r = 0; r < 4; ++r) {
            float s = 0.f;
#pragma unroll
            for (int c = 0; c < 8; ++c) s = fmaf(fmaxf(acc[r][c], 0.f), w2[c], s);
            pz[r] = s;
        }
#pragma unroll
        for (int m = 1; m <= 16; m <<= 1) {
#pragma unroll
            for (int r = 0; r < 4; ++r) pz[r] += __shfl_xor(pz[r], m, 64);
        }
        if (colg == 0) {
#pragma unroll
            for (int r = 0; r < 4; ++r) zs[rowg * 4 + r] = pz[r] + b2v;
        }
        __syncthreads();

        // fp32 decisions; mark rows needing fp64
        if (tid < RT) {
            const int idx = T * RT + tid;
            if (idx < cnt) {
                const float z = zs[tid];
                if (fabsf(z) < TAU2) {
                    need64[tid] = 1;
                } else if (z > 0.f) {
                    const int e = eL[tid];
                    atomicMax(&last[srcIdx[e]], e + 1);
                    atomicMax(&last[dstIdx[e]], e + 1);
                }
            }
        }
        __syncthreads();

        // inline fp64 decision (rare: ~dozens of edges total)
        for (int r = 0; r < RT; ++r) {
            if (!need64[r]) continue;          // wave-uniform branch
            const int j = tid;
            double h0 = 0.0, h1 = 0.0;
            for (int k = 0; k < K2D; k += 2) {
                h0 += (double)P[r * PST + k]     * (double)W1[(k)     * HH + j];
                h1 += (double)P[r * PST + k + 1] * (double)W1[(k + 1) * HH + j];
            }
            const double h = (double)b1[j] + h0 + h1;
            double v = (h > 0.0) ? h * (double)W2[j] : 0.0;
#pragma unroll
            for (int m = 1; m <= 32; m <<= 1) v += __shfl_xor(v, m, 64);
            if ((tid & 63) == 0) wsumd[tid >> 6] = v;
            __syncthreads();
            if (tid == 0) {
                const double z = wsumd[0] + wsumd[1] + wsumd[2] + wsumd[3] + (double)b2v;
                if (z > 0.0) {
                    const int e = eL[r];
                    atomicMax(&last[srcIdx[e]], e + 1);
                    atomicMax(&last[dstIdx[e]], e + 1);
                }
            }
            __syncthreads();
        }
        __syncthreads();   // protect P/eL before next tile overwrite
    }
}

// ---------------------------------------------------------------------------
// Resolver per NODE (winning edge only), both layers bf16 MFMA.
// ---------------------------------------------------------------------------
template<int BF>
__global__ __launch_bounds__(256) void res_kernel(
    const float* __restrict__ emb, const ushort* __restrict__ embbf,
    const int* __restrict__ srcIdx, const int* __restrict__ dstIdx,
    const ushort* __restrict__ w1s, const float* __restrict__ b1,
    const ushort* __restrict__ w2s, const float* __restrict__ b2,
    const int* __restrict__ last,
    float* __restrict__ outRes)
{
    __shared__ __align__(16) ushort A_lds[TE * K2D];
    __shared__ int lastL[TE];
    const int tid = threadIdx.x;
    const int n0 = blockIdx.x * TE;
    const int wv = tid >> 6;
    const int lane = tid & 63;

    if (tid < TE) {
        const int n = n0 + tid;
        lastL[tid] = (n < NN) ? last[n] : 0;
    }
    if (BF) {
        const int r = wv * 16 + (lane & 15);
        const int n = n0 + r;
        int e = 0;
        if (n < NN) { const int lv = last[n]; if (lv > 0) e = lv - 1; }
        const int ns = srcIdx[e], nd = dstIdx[e];
        const int ko = (lane >> 4) * 8;
#pragma unroll
        for (int s = 0; s < 8; ++s) {
            const int node = (s < 4) ? ns : nd;
            const ushort* g = embbf + (size_t)node * DD + (s & 3) * 32 + ko;
            __builtin_amdgcn_global_load_lds((const g1_void_t*)g,
                                             (lds_void_t*)&A_lds[(wv * 8 + s) * 512],
                                             16, 0, 0);
        }
    } else {
        const int r = tid >> 2, q = tid & 3;
        const int n = n0 + r;
        int e = 0;
        if (n < NN) { const int l = last[n]; if (l > 0) e = l - 1; }
        const int node = (q < 2) ? srcIdx[e] : dstIdx[e];
        const float4* s4 = (const float4*)(emb + (size_t)node * DD + (q & 1) * 64);
#pragma unroll
        for (int u = 0; u < 16; ++u) {
            const float4 v = s4[u];
            const int k0 = q * 64 + u * 4;
            uint2 p;
            p.x = (uint)f2bf(v.x) | ((uint)f2bf(v.y) << 16);
            p.y = (uint)f2bf(v.z) | ((uint)f2bf(v.w) << 16);
            *(uint2*)&A_lds[stageOff(r, k0)] = p;
        }
    }
    __syncthreads();

    const int lc = lane & 15, lg = lane >> 4;

    f32x4 acc[4][4] = {};
    {
        const ushort* wbase = w1s + (size_t)(wv * 4) * 8 * 512;
#pragma unroll 2
        for (int t = 0; t < 8; ++t) {
            bf16x8 af[4], bfr[4];
#pragma unroll
            for (int m = 0; m < 4; ++m)
                af[m] = *(const bf16x8*)&A_lds[(m * 8 + t) * 512 + lane * 8];
#pragma unroll
            for (int n = 0; n < 4; ++n)
                bfr[n] = *(const bf16x8*)(wbase + (n * 8 + t) * 512 + lane * 8);
#pragma unroll
            for (int m = 0; m < 4; ++m)
#pragma unroll
                for (int n = 0; n < 4; ++n)
                    acc[m][n] = __builtin_amdgcn_mfma_f32_16x16x32_bf16(af[m], bfr[n], acc[m][n], 0, 0, 0);
        }
    }
    float b1v[4];
#pragma unroll
    for (int n = 0; n < 4; ++n) b1v[n] = b1[wv * 64 + n * 16 + lc];

    __syncthreads();
#pragma unroll
    for (int m = 0; m < 4; ++m)
#pragma unroll
        for (int n = 0; n < 4; ++n) {
            const int hcol = wv * 64 + n * 16 + lc;
#pragma unroll
            for (int r = 0; r < 4; ++r) {
                const int row = m * 16 + lg * 4 + r;
                A_lds[stageOff(row, hcol)] = f2bf(fmaxf(acc[m][n][r] + b1v[n], 0.f));
            }
        }
    __syncthreads();

    f32x4 acc2[4][2] = {};
    {
        const ushort* wbase = w2s + (size_t)(wv * 2) * 8 * 512;
#pragma unroll 2
        for (int t = 0; t < 8; ++t) {
            bf16x8 af[4], bfr[2];
#pragma unroll
            for (int m = 0; m < 4; ++m)
                af[m] = *(const bf16x8*)&A_lds[(m * 8 + t) * 512 + lane * 8];
#pragma unroll
            for (int n = 0; n < 2; ++n)
                bfr[n] = *(const bf16x8*)(wbase + (n * 8 + t) * 512 + lane * 8);
#pragma unroll
            for (int m = 0; m < 4; ++m)
#pragma unroll
                for (int n = 0; n < 2; ++n)
                    acc2[m][n] = __builtin_amdgcn_mfma_f32_16x16x32_bf16(af[m], bfr[n], acc2[m][n], 0, 0, 0);
        }
    }
    float b2v[2];
#pragma unroll
    for (int n = 0; n < 2; ++n) b2v[n] = b2[(wv * 2 + n) * 16 + lc];

#pragma unroll
    for (int m = 0; m < 4; ++m)
#pragma unroll
        for (int r = 0; r < 4; ++r) {
            const int row = m * 16 + lg * 4 + r;
            const int n = n0 + row;
            if (n >= NN) continue;
            const bool hit = lastL[row] > 0;
#pragma unroll
            for (int c = 0; c < 2; ++c) {
                const int col = (wv * 2 + c) * 16 + lc;
                const float ev = emb[(size_t)n * DD + col];
                outRes[(size_t)n * DD + col] =
                    hit ? (ev + acc2[m][c][r] + b2v[c]) * 0.5f : ev;
            }
        }
}

// ---------------------------------------------------------------------------
extern "C" void kernel_launch(void* const* d_in, const int* in_sizes, int n_in,
                              void* d_out, int out_size, void* d_ws, size_t ws_size,
                              hipStream_t stream)
{
    const float* emb = (const float*)d_in[0];
    const int*   edge = (const int*)d_in[1];
    const float* Wd1 = (const float*)d_in[2];
    const float* bd1 = (const float*)d_in[3];
    const float* Wd2 = (const float*)d_in[4];
    const float* bd2 = (const float*)d_in[5];
    const float* Wr1 = (const float*)d_in[6];
    const float* br1 = (const float*)d_in[7];
    const float* Wr2 = (const float*)d_in[8];
    const float* br2 = (const float*)d_in[9];

    const int* srcIdx = edge;
    const int* dstIdx = edge + EE;

    float* outRes = (float*)d_out;
    float* scores = outRes + (size_t)NN * DD;

    // ws: last[50000+pad] | flagCount | wd1s | wr1s | wr2s | flagList | embbf
    int* last = (int*)d_ws;
    int* flagCount = last + 50112;
    ushort* wd1s = (ushort*)(last + 50176);    // 128 KB
    ushort* wr1s = wd1s + 65536;               // 128 KB
    ushort* wr2s = wr1s + 65536;               // 64 KB
    int* flagList = (int*)(wr2s + 32768);      // 256 KB
    ushort* embbf = (ushort*)(flagList + 65536);   // 12.8 MB

    const size_t base   = 50176u * 4 + (65536u + 65536u + 32768u) * 2 + 65536u * 4;
    const size_t needBF = base + (size_t)NN * DD * 2;
    const int useBF = (ws_size >= needBF) ? 1 : 0;

    int flagCap = 65536;
    if (ws_size < base) {
        long avail = ((long)ws_size - (long)(base - 65536u * 4)) / 4;
        flagCap = avail < 0 ? 0 : (int)avail;
    }

    hipMemsetAsync(d_ws, 0, 50176 * sizeof(int), stream);   // last + flagCount

    prep_kernel<<<3205, 256, 0, stream>>>(emb, embbf, useBF,
                                          Wd1, wd1s, Wr1, wr1s, Wr2, wr2s);

    if (useBF) {
        det_kernel<1><<<EE / TE, 256, 0, stream>>>(emb, embbf, srcIdx, dstIdx,
                                                   wd1s, bd1, Wd2, bd2,
                                                   scores, last, flagCount, flagList, flagCap);
    } else {
        det_kernel<0><<<EE / TE, 256, 0, stream>>>(emb, embbf, srcIdx, dstIdx,
                                                   wd1s, bd1, Wd2, bd2,
                                                   scores, last, flagCount, flagList, flagCap);
    }
    refine_kernel<<<1024, 256, 0, stream>>>(emb, srcIdx, dstIdx,
                                            Wd1, bd1, Wd2, bd2,
                                            last, flagCount, flagList, flagCap);
    if (useBF) {
        res_kernel<1><<<(NN + TE - 1) / TE, 256, 0, stream>>>(emb, embbf, srcIdx, dstIdx,
                                                              wr1s, br1, wr2s, br2,
                                                              last, outRes);
    } else {
        res_kernel<0><<<(NN + TE - 1) / TE, 256, 0, stream>>>(emb, embbf, srcIdx, dstIdx,
                                                              wr1s, br1, wr2s, br2,
                                                              last, outRes);
    }
}